// Round 1
// baseline (358.984 us; speedup 1.0000x reference)
//
#include <hip/hip_runtime.h>
#include <cstdint>
#include <cstddef>

#define T_SEQ 2048
#define DMODEL 2048
#define HQ 16
#define HKV 4
#define HD 128

typedef __attribute__((ext_vector_type(4))) float f32x4;
typedef __attribute__((ext_vector_type(8))) short bf16x8;
typedef __attribute__((ext_vector_type(4))) short short4v;

__device__ __forceinline__ short f2bf(float f) {
  unsigned u = __builtin_bit_cast(unsigned, f);
  u = (u + 0x7FFFu + ((u >> 16) & 1u)) >> 16;
  return (short)u;
}
__device__ __forceinline__ float bf2f(short s) {
  unsigned u = ((unsigned)(unsigned short)s) << 16;
  return __builtin_bit_cast(float, u);
}

__device__ __forceinline__ void g2lds16(const void* g, void* l) {
  __builtin_amdgcn_global_load_lds(
      (const __attribute__((address_space(1))) void*)g,
      (__attribute__((address_space(3))) void*)l, 16, 0, 0);
}

// ---------------- convert f32 -> bf16 ----------------
__global__ void cvt_kernel(const float* __restrict__ src, short* __restrict__ dst, int n) {
  int idx = blockIdx.x * 256 + threadIdx.x;
  int i = idx * 4;
  if (i >= n) return;
  float4 v = *(const float4*)(src + i);
  short4v o;
  o[0] = f2bf(v.x); o[1] = f2bf(v.y); o[2] = f2bf(v.z); o[3] = f2bf(v.w);
  *(short4v*)(dst + i) = o;
}

// ---------------- transpose + convert: src [R][C] f32 -> dst [C][R] bf16 ----------------
__global__ void transpose_cvt(const float* __restrict__ src, short* __restrict__ dst, int R, int C) {
  __shared__ float tile[32][33];
  int c0 = blockIdx.x * 32, r0 = blockIdx.y * 32;
  int tx = threadIdx.x, ty = threadIdx.y;
  #pragma unroll
  for (int i = 0; i < 32; i += 8)
    tile[ty + i][tx] = src[(size_t)(r0 + ty + i) * C + c0 + tx];
  __syncthreads();
  #pragma unroll
  for (int i = 0; i < 32; i += 8)
    dst[(size_t)(c0 + ty + i) * R + r0 + tx] = f2bf(tile[tx][ty + i]);
}

// ---------------- GEMM: C[M][N] = A[M][K] * B[K][N], BT is B transposed [N][K] ----------------
__global__ __launch_bounds__(256, 2) void gemm_kernel(
    const short* __restrict__ A, const short* __restrict__ BT,
    void* __restrict__ Cout, int M, int N, int K, int outF32)
{
  __shared__ short As[128 * 32];
  __shared__ short Bs[128 * 32];
  const int tid = threadIdx.x;
  const int lane = tid & 63, w = tid >> 6;
  const int l15 = lane & 15, g = lane >> 4;
  const int m0 = blockIdx.y * 128, n0 = blockIdx.x * 128;
  const int wm = (w >> 1) * 64, wn = (w & 1) * 64;

  f32x4 acc[4][4] = {};

  for (int k0 = 0; k0 < K; k0 += 32) {
    __syncthreads();
    #pragma unroll
    for (int call = 0; call < 2; call++) {
      int tau = call * 256 + tid;
      int row = tau >> 2, c = tau & 3;
      int swz = (row & 3) ^ ((row >> 2) & 3);
      g2lds16(A + (size_t)(m0 + row) * K + k0 + ((c ^ swz) << 3),
              (char*)As + call * 4096 + w * 1024);
      g2lds16(BT + (size_t)(n0 + row) * K + k0 + ((c ^ swz) << 3),
              (char*)Bs + call * 4096 + w * 1024);
    }
    __syncthreads();
    bf16x8 af[4], bfr[4];
    #pragma unroll
    for (int mi = 0; mi < 4; mi++) {
      int row = wm + mi * 16 + l15;
      int ch = g ^ ((row & 3) ^ ((row >> 2) & 3));
      af[mi] = *(const bf16x8*)(As + row * 32 + ch * 8);
    }
    #pragma unroll
    for (int ni = 0; ni < 4; ni++) {
      int row = wn + ni * 16 + l15;
      int ch = g ^ ((row & 3) ^ ((row >> 2) & 3));
      bfr[ni] = *(const bf16x8*)(Bs + row * 32 + ch * 8);
    }
    #pragma unroll
    for (int mi = 0; mi < 4; mi++)
      #pragma unroll
      for (int ni = 0; ni < 4; ni++)
        acc[mi][ni] = __builtin_amdgcn_mfma_f32_16x16x32_bf16(af[mi], bfr[ni], acc[mi][ni], 0, 0, 0);
  }

  if (outF32) {
    float* C = (float*)Cout;
    #pragma unroll
    for (int mi = 0; mi < 4; mi++)
      #pragma unroll
      for (int r = 0; r < 4; r++) {
        int m = m0 + wm + mi * 16 + g * 4 + r;
        #pragma unroll
        for (int ni = 0; ni < 4; ni++)
          C[(size_t)m * N + n0 + wn + ni * 16 + l15] = acc[mi][ni][r];
      }
  } else {
    short* C = (short*)Cout;
    #pragma unroll
    for (int mi = 0; mi < 4; mi++)
      #pragma unroll
      for (int r = 0; r < 4; r++) {
        int m = m0 + wm + mi * 16 + g * 4 + r;
        #pragma unroll
        for (int ni = 0; ni < 4; ni++)
          C[(size_t)m * N + n0 + wn + ni * 16 + l15] = f2bf(acc[mi][ni][r]);
      }
  }
}

// ---------------- RoPE in-place on [B*T][NH][128] bf16, fold scale into output ----------------
__global__ void rope_kernel(short* __restrict__ buf, int NH, float scale, int npairs) {
  int idx = blockIdx.x * 256 + threadIdx.x;
  if (idx >= npairs) return;
  int i = idx & 63;
  int th = idx >> 6;                 // (b*T + t)*NH + h
  int t = (th / NH) % T_SEQ;
  size_t base = (size_t)th * 128;
  float invf = exp2f(-(float)i * 0.20762050593046014f);  // 10000^(-i/64)
  float theta = (float)t * invf;
  float sn, cs;
  sincosf(theta, &sn, &cs);
  float a = bf2f(buf[base + i]);
  float b = bf2f(buf[base + 64 + i]);
  buf[base + i]      = f2bf((a * cs - b * sn) * scale);
  buf[base + 64 + i] = f2bf((b * cs + a * sn) * scale);
}

// ---------------- Flash attention (causal, GQA), swapped-operand MFMA ----------------
// q: [B,T,HQ,128] bf16 (pre-scaled by MULT*log2e, roped); k: [B,T,HKV,128] roped; v: [B,T,HKV,128]
// out: [B,T,HQ,128] bf16. Block: 256 thr (4 waves), 128 q-rows/block (32/wave), KV tile 64.
__global__ __launch_bounds__(256, 2) void attn_kernel(
    const short* __restrict__ qg, const short* __restrict__ kg,
    const short* __restrict__ vg, short* __restrict__ og)
{
  __shared__ short Ks[64 * 128];    // [kv][d], d-chunks XOR-swizzled by kv&7
  __shared__ short Vt[128 * 68];    // V^T [d][kv], row stride 68 (pad)
  const int tid = threadIdx.x;
  const int lane = tid & 63, w = tid >> 6;
  const int l15 = lane & 15, g = lane >> 4;
  const int qt0 = blockIdx.x * 128;
  const int h = blockIdx.y, b = blockIdx.z, hk = h >> 2;
  const int qw0 = qt0 + w * 32;

  // Q fragments in registers: [qc][ks], lane holds Q[qrow=l15][d=ks*32+8g..+7]
  bf16x8 qf[2][4];
  #pragma unroll
  for (int qc = 0; qc < 2; qc++) {
    size_t t = (size_t)b * T_SEQ + qw0 + qc * 16 + l15;
    const short* qp = qg + (t * HQ + h) * HD;
    #pragma unroll
    for (int ks = 0; ks < 4; ks++)
      qf[qc][ks] = *(const bf16x8*)(qp + ks * 32 + g * 8);
  }

  f32x4 of[2][8] = {};              // O^T acc [qc][dc]: row d=dc*16+4g+r, col q=l15
  float m2[2] = {-INFINITY, -INFINITY};
  float ls[2] = {0.f, 0.f};

  const int kvend = qt0 + 128;
  for (int kv0 = 0; kv0 < kvend; kv0 += 64) {
    __syncthreads();
    // stage K via global_load_lds (source pre-swizzled chunks)
    #pragma unroll
    for (int call = 0; call < 4; call++) {
      int tau = call * 256 + tid;
      int kv = tau >> 4, c = tau & 15;
      g2lds16(kg + ((size_t)(b * T_SEQ + kv0 + kv) * HKV + hk) * HD + ((c ^ (kv & 7)) << 3),
              (char*)Ks + call * 4096 + w * 1024);
    }
    // stage V^T (register transpose): coalesced-ish 64B/row reads, 4-way-conflict writes
    for (int u = tid; u < 1024; u += 256) {
      int kv = (u & 15) | ((u >> 8) << 4);
      int d8 = (u >> 4) & 15;
      bf16x8 val = *(const bf16x8*)(vg + ((size_t)(b * T_SEQ + kv0 + kv) * HKV + hk) * HD + d8 * 8);
      int base = (d8 * 8) * 68 + kv;
      #pragma unroll
      for (int e = 0; e < 8; e++) Vt[base + e * 68] = val[e];
    }
    __syncthreads();

    if (kv0 <= qw0 + 31) {
      // S^T = K * Q^T : [kv 64 x q 32] per wave, frag rows kv=kt*16+l15 wait no:
      // A=K frag: row kv=kt*16+l15? -> A row = l15 within fragment kt. k=d contiguous chunks.
      f32x4 sacc[4][2] = {};
      #pragma unroll
      for (int ks = 0; ks < 4; ks++) {
        bf16x8 kf[4];
        #pragma unroll
        for (int kt = 0; kt < 4; kt++) {
          int row = kt * 16 + l15;
          int ch = (ks * 4 + g) ^ (row & 7);
          kf[kt] = *(const bf16x8*)(Ks + row * 128 + ch * 8);
        }
        #pragma unroll
        for (int kt = 0; kt < 4; kt++)
          #pragma unroll
          for (int qc = 0; qc < 2; qc++)
            sacc[kt][qc] = __builtin_amdgcn_mfma_f32_16x16x32_bf16(kf[kt], qf[qc][ks], sacc[kt][qc], 0, 0, 0);
      }
      const bool needmask = (kv0 + 63) > qw0;
      #pragma unroll
      for (int qc = 0; qc < 2; qc++) {
        int qpos = qw0 + qc * 16 + l15;
        float vmax = -INFINITY;
        #pragma unroll
        for (int kt = 0; kt < 4; kt++)
          #pragma unroll
          for (int r = 0; r < 4; r++) {
            int kvpos = kv0 + kt * 16 + g * 4 + r;
            float sv = sacc[kt][qc][r];
            if (needmask && kvpos > qpos) sv = -INFINITY;
            sacc[kt][qc][r] = sv;
            vmax = fmaxf(vmax, sv);
          }
        vmax = fmaxf(vmax, __shfl_xor(vmax, 16));
        vmax = fmaxf(vmax, __shfl_xor(vmax, 32));
        float mnew = fmaxf(m2[qc], vmax);
        float resc = exp2f(m2[qc] - mnew);
        m2[qc] = mnew;
        float lsum = 0.f;
        #pragma unroll
        for (int kt = 0; kt < 4; kt++)
          #pragma unroll
          for (int r = 0; r < 4; r++) {
            float p = exp2f(sacc[kt][qc][r] - mnew);
            sacc[kt][qc][r] = p;
            lsum += p;
          }
        lsum += __shfl_xor(lsum, 16);
        lsum += __shfl_xor(lsum, 32);
        ls[qc] = ls[qc] * resc + lsum;
        #pragma unroll
        for (int dc = 0; dc < 8; dc++) of[qc][dc] *= resc;
      }
      // pack P (two-halves k-mapping matches S^T register layout)
      bf16x8 pb[2][2];
      #pragma unroll
      for (int ktw = 0; ktw < 2; ktw++)
        #pragma unroll
        for (int qc = 0; qc < 2; qc++) {
          bf16x8 pv;
          #pragma unroll
          for (int j = 0; j < 4; j++) {
            pv[j]     = f2bf(sacc[2 * ktw][qc][j]);
            pv[4 + j] = f2bf(sacc[2 * ktw + 1][qc][j]);
          }
          pb[ktw][qc] = pv;
        }
      // O^T += V^T * P
      #pragma unroll
      for (int ktw = 0; ktw < 2; ktw++)
        #pragma unroll
        for (int dc = 0; dc < 8; dc++) {
          int drow = dc * 16 + l15;
          const short* vp = Vt + drow * 68 + ktw * 32 + g * 4;
          short4v v1 = *(const short4v*)(vp);
          short4v v2 = *(const short4v*)(vp + 16);
          bf16x8 vf;
          #pragma unroll
          for (int j = 0; j < 4; j++) { vf[j] = v1[j]; vf[4 + j] = v2[j]; }
          #pragma unroll
          for (int qc = 0; qc < 2; qc++)
            of[qc][dc] = __builtin_amdgcn_mfma_f32_16x16x32_bf16(vf, pb[ktw][qc], of[qc][dc], 0, 0, 0);
        }
    }
  }

  // epilogue: normalize and store O (lane: q=l15, d=dc*16+4g+r)
  #pragma unroll
  for (int qc = 0; qc < 2; qc++) {
    float inv = 1.0f / ls[qc];
    size_t t = (size_t)b * T_SEQ + qw0 + qc * 16 + l15;
    short* op = og + (t * HQ + h) * HD;
    #pragma unroll
    for (int dc = 0; dc < 8; dc++) {
      short4v o;
      #pragma unroll
      for (int r = 0; r < 4; r++) o[r] = f2bf(of[qc][dc][r] * inv);
      *(short4v*)(op + dc * 16 + g * 4) = o;
    }
  }
}

extern "C" void kernel_launch(void* const* d_in, const int* in_sizes, int n_in,
                              void* d_out, int out_size, void* d_ws, size_t ws_size,
                              hipStream_t stream) {
  (void)in_sizes; (void)n_in; (void)out_size; (void)ws_size;
  const float* x  = (const float*)d_in[0];
  const float* Wq = (const float*)d_in[2];
  const float* Wk = (const float*)d_in[3];
  const float* Wv = (const float*)d_in[4];
  const float* Wo = (const float*)d_in[5];

  char* ws = (char*)d_ws;
  short* xb  = (short*)(ws);                      // 16 MB  [4096][2048]
  short* wqT = (short*)(ws + 16777216);           // 8 MB   [2048][2048]
  short* wkT = (short*)(ws + 25165824);           // 2 MB   [512][2048]
  short* wvT = (short*)(ws + 27262976);           // 2 MB   [512][2048]
  short* woT = (short*)(ws + 29360128);           // 8 MB   [2048][2048]
  short* qb  = (short*)(ws + 37748736);           // 16 MB  [B,T,HQ,128]
  short* kb  = (short*)(ws + 54525952);           // 4 MB   [B,T,HKV,128]
  short* vb  = (short*)(ws + 58720256);           // 4 MB   [B,T,HKV,128]
  short* ab  = (short*)(ws + 62914560);           // 16 MB  [4096][2048]

  const float MULT = 0.08838834764831845f;
  const float LOG2E = 1.4426950408889634f;
  const float QSCALE = MULT * LOG2E;

  dim3 tb(32, 8);
  cvt_kernel<<<8192, 256, 0, stream>>>(x, xb, 8388608);
  transpose_cvt<<<dim3(64, 64), tb, 0, stream>>>(Wq, wqT, 2048, 2048);
  transpose_cvt<<<dim3(16, 64), tb, 0, stream>>>(Wk, wkT, 2048, 512);
  transpose_cvt<<<dim3(16, 64), tb, 0, stream>>>(Wv, wvT, 2048, 512);
  transpose_cvt<<<dim3(64, 64), tb, 0, stream>>>(Wo, woT, 2048, 2048);

  gemm_kernel<<<dim3(16, 32), 256, 0, stream>>>(xb, wqT, qb, 4096, 2048, 2048, 0);
  gemm_kernel<<<dim3(4, 32), 256, 0, stream>>>(xb, wkT, kb, 4096, 512, 2048, 0);
  gemm_kernel<<<dim3(4, 32), 256, 0, stream>>>(xb, wvT, vb, 4096, 512, 2048, 0);

  rope_kernel<<<16384, 256, 0, stream>>>(qb, HQ, QSCALE, 4194304);
  rope_kernel<<<4096, 256, 0, stream>>>(kb, HKV, 1.0f, 1048576);

  attn_kernel<<<dim3(16, 16, 2), 256, 0, stream>>>(qb, kb, vb, ab);

  gemm_kernel<<<dim3(16, 32), 256, 0, stream>>>(ab, woT, d_out, 4096, 2048, 2048, 1);
}

// Round 2
// 262.254 us; speedup vs baseline: 1.3688x; 1.3688x over previous
//
#include <hip/hip_runtime.h>
#include <cstdint>
#include <cstddef>

#define T_SEQ 2048
#define DMODEL 2048
#define HQ 16
#define HKV 4
#define HD 128

typedef __attribute__((ext_vector_type(4))) float f32x4;
typedef __attribute__((ext_vector_type(8))) short bf16x8;
typedef __attribute__((ext_vector_type(4))) short short4v;

__device__ __forceinline__ short f2bf(float f) {
  unsigned u = __builtin_bit_cast(unsigned, f);
  u = (u + 0x7FFFu + ((u >> 16) & 1u)) >> 16;
  return (short)u;
}
__device__ __forceinline__ float bf2f(short s) {
  unsigned u = ((unsigned)(unsigned short)s) << 16;
  return __builtin_bit_cast(float, u);
}

__device__ __forceinline__ void g2lds16(const void* g, void* l) {
  __builtin_amdgcn_global_load_lds(
      (const __attribute__((address_space(1))) void*)g,
      (__attribute__((address_space(3))) void*)l, 16, 0, 0);
}

// ---------------- convert f32 -> bf16 ----------------
__global__ void cvt_kernel(const float* __restrict__ src, short* __restrict__ dst, int n) {
  int idx = blockIdx.x * 256 + threadIdx.x;
  int i = idx * 4;
  if (i >= n) return;
  float4 v = *(const float4*)(src + i);
  short4v o;
  o[0] = f2bf(v.x); o[1] = f2bf(v.y); o[2] = f2bf(v.z); o[3] = f2bf(v.w);
  *(short4v*)(dst + i) = o;
}

// ---------------- transpose + convert: src [R][C] f32 -> dst [C][R] bf16 ----------------
__global__ void transpose_cvt(const float* __restrict__ src, short* __restrict__ dst, int R, int C) {
  __shared__ float tile[32][33];
  int c0 = blockIdx.x * 32, r0 = blockIdx.y * 32;
  int tx = threadIdx.x, ty = threadIdx.y;
  #pragma unroll
  for (int i = 0; i < 32; i += 8)
    tile[ty + i][tx] = src[(size_t)(r0 + ty + i) * C + c0 + tx];
  __syncthreads();
  #pragma unroll
  for (int i = 0; i < 32; i += 8)
    dst[(size_t)(c0 + ty + i) * R + r0 + tx] = f2bf(tile[tx][ty + i]);
}

// ---------------- GEMM: C = A[M][K] * B[K][N], BT is B transposed [N][K] ----------------
// MODE 0: bf16 C0, ldc=N.  MODE 1: f32 C0, ldc=N.  MODE 2: qkv split (N=3072):
//   n<2048 -> C0 (ldc 2048), n<2560 -> C1 (ldc 512), else C2 (ldc 512); bf16.
template <int MODE>
__global__ __launch_bounds__(256, 2) void gemm_kernel(
    const short* __restrict__ A, const short* __restrict__ BT,
    void* __restrict__ C0, void* __restrict__ C1, void* __restrict__ C2,
    int M, int N, int K)
{
  __shared__ short As[128 * 32];
  __shared__ short Bs[128 * 32];
  const int tid = threadIdx.x;
  const int lane = tid & 63, w = tid >> 6;
  const int l15 = lane & 15, g = lane >> 4;
  const int m0 = blockIdx.y * 128, n0 = blockIdx.x * 128;
  const int wm = (w >> 1) * 64, wn = (w & 1) * 64;

  f32x4 acc[4][4] = {};

  for (int k0 = 0; k0 < K; k0 += 32) {
    __syncthreads();
    #pragma unroll
    for (int call = 0; call < 2; call++) {
      int tau = call * 256 + tid;
      int row = tau >> 2, c = tau & 3;
      int swz = (row & 3) ^ ((row >> 2) & 3);
      g2lds16(A + (size_t)(m0 + row) * K + k0 + ((c ^ swz) << 3),
              (char*)As + call * 4096 + w * 1024);
      g2lds16(BT + (size_t)(n0 + row) * K + k0 + ((c ^ swz) << 3),
              (char*)Bs + call * 4096 + w * 1024);
    }
    __syncthreads();
    bf16x8 af[4], bfr[4];
    #pragma unroll
    for (int mi = 0; mi < 4; mi++) {
      int row = wm + mi * 16 + l15;
      int ch = g ^ ((row & 3) ^ ((row >> 2) & 3));
      af[mi] = *(const bf16x8*)(As + row * 32 + ch * 8);
    }
    #pragma unroll
    for (int ni = 0; ni < 4; ni++) {
      int row = wn + ni * 16 + l15;
      int ch = g ^ ((row & 3) ^ ((row >> 2) & 3));
      bfr[ni] = *(const bf16x8*)(Bs + row * 32 + ch * 8);
    }
    #pragma unroll
    for (int mi = 0; mi < 4; mi++)
      #pragma unroll
      for (int ni = 0; ni < 4; ni++)
        acc[mi][ni] = __builtin_amdgcn_mfma_f32_16x16x32_bf16(af[mi], bfr[ni], acc[mi][ni], 0, 0, 0);
  }

  if (MODE == 1) {
    float* C = (float*)C0;
    #pragma unroll
    for (int mi = 0; mi < 4; mi++)
      #pragma unroll
      for (int r = 0; r < 4; r++) {
        int m = m0 + wm + mi * 16 + g * 4 + r;
        #pragma unroll
        for (int ni = 0; ni < 4; ni++)
          C[(size_t)m * N + n0 + wn + ni * 16 + l15] = acc[mi][ni][r];
      }
  } else {
    short* Cb; int ldc, nc;
    if (MODE == 0) { Cb = (short*)C0; ldc = N; nc = n0; }
    else {
      if (n0 < 2048)      { Cb = (short*)C0; ldc = 2048; nc = n0; }
      else if (n0 < 2560) { Cb = (short*)C1; ldc = 512;  nc = n0 - 2048; }
      else                { Cb = (short*)C2; ldc = 512;  nc = n0 - 2560; }
    }
    #pragma unroll
    for (int mi = 0; mi < 4; mi++)
      #pragma unroll
      for (int r = 0; r < 4; r++) {
        int m = m0 + wm + mi * 16 + g * 4 + r;
        #pragma unroll
        for (int ni = 0; ni < 4; ni++)
          Cb[(size_t)m * ldc + nc + wn + ni * 16 + l15] = f2bf(acc[mi][ni][r]);
      }
  }
}

// ---------------- RoPE in-place on [B*T][NH][128] bf16, fold scale into output ----------------
__global__ void rope_kernel(short* __restrict__ buf, int NH, float scale, int npairs) {
  int idx = blockIdx.x * 256 + threadIdx.x;
  if (idx >= npairs) return;
  int i = idx & 63;
  int th = idx >> 6;                 // (b*T + t)*NH + h
  int t = (th / NH) % T_SEQ;
  size_t base = (size_t)th * 128;
  float invf = exp2f(-(float)i * 0.20762050593046014f);  // 10000^(-i/64)
  float theta = (float)t * invf;
  float sn, cs;
  sincosf(theta, &sn, &cs);
  float a = bf2f(buf[base + i]);
  float b = bf2f(buf[base + 64 + i]);
  buf[base + i]      = f2bf((a * cs - b * sn) * scale);
  buf[base + 64 + i] = f2bf((b * cs + a * sn) * scale);
}

// ---------------- Flash attention (causal, GQA), swapped-operand MFMA ----------------
// q: [B,T,HQ,128] bf16 (pre-scaled by MULT*log2e, roped); k,v: [B,T,HKV,128]
// Block: 256 thr (4 waves), 128 q-rows/block (32/wave), KV tile 64, K double-buffered.
__global__ __launch_bounds__(256, 2) void attn_kernel(
    const short* __restrict__ qg, const short* __restrict__ kg,
    const short* __restrict__ vg, short* __restrict__ og)
{
  __shared__ short Ks[2][64 * 128];  // [kv][d], d-chunks XOR-swizzled by kv&7
  __shared__ short Vt[128 * 68];     // V^T [d][kv], row stride 68 (pad)
  const int tid = threadIdx.x;
  const int lane = tid & 63, w = tid >> 6;
  const int l15 = lane & 15, g = lane >> 4;
  const int b = blockIdx.z;
  const int qti = b ? (15 - (int)blockIdx.x) : (int)blockIdx.x;  // causal load balance
  const int qt0 = qti * 128;
  const int h = blockIdx.y, hk = h >> 2;
  const int qw0 = qt0 + w * 32;

  // Q fragments in registers: [qc][ks], lane holds Q[qrow=l15][d=ks*32+8g..+7]
  bf16x8 qf[2][4];
  #pragma unroll
  for (int qc = 0; qc < 2; qc++) {
    size_t t = (size_t)b * T_SEQ + qw0 + qc * 16 + l15;
    const short* qp = qg + (t * HQ + h) * HD;
    #pragma unroll
    for (int ks = 0; ks < 4; ks++)
      qf[qc][ks] = *(const bf16x8*)(qp + ks * 32 + g * 8);
  }

  f32x4 of[2][8] = {};              // O^T acc [qc][dc]: row d=dc*16+4g+r, col q=l15
  float m2[2] = {-INFINITY, -INFINITY};
  float ls[2] = {0.f, 0.f};

  const short* kbase = kg + ((size_t)b * T_SEQ * HKV + hk) * HD;
  const short* vbase = vg + ((size_t)b * T_SEQ * HKV + hk) * HD;
  const int kv4 = (tid & 15) * 4, d8s = (tid >> 4) * 8;
  const int nt = (qt0 + 128) >> 6;

  bf16x8 vr[4];

  auto stageK = [&](int t, int nb) {
    #pragma unroll
    for (int call = 0; call < 4; call++) {
      int tau = call * 256 + tid;
      int kv = tau >> 4, c = tau & 15;
      g2lds16(kbase + (size_t)(t * 64 + kv) * (HKV * HD) + ((c ^ (kv & 7)) << 3),
              (char*)Ks[nb] + call * 4096 + w * 1024);
    }
  };
  auto loadV = [&](int t) {
    #pragma unroll
    for (int i = 0; i < 4; i++)
      vr[i] = *(const bf16x8*)(vbase + (size_t)(t * 64 + kv4 + i) * (HKV * HD) + d8s);
  };
  auto writeV = [&]() {
    #pragma unroll
    for (int e = 0; e < 8; e++) {
      short4v t4;
      t4[0] = vr[0][e]; t4[1] = vr[1][e]; t4[2] = vr[2][e]; t4[3] = vr[3][e];
      *(short4v*)(&Vt[(d8s + e) * 68 + kv4]) = t4;
    }
  };

  // prologue: stage tile 0
  stageK(0, 0);
  loadV(0);
  __syncthreads();
  writeV();
  __syncthreads();

  int cur = 0;
  for (int t = 0; t < nt; t++) {
    const int kv0 = t * 64;
    const bool haveNext = (t + 1 < nt);
    if (haveNext) { loadV(t + 1); stageK(t + 1, cur ^ 1); }

    if (kv0 <= qw0 + 31) {
      const short* Kc = Ks[cur];
      f32x4 sacc[4][2] = {};
      __builtin_amdgcn_s_setprio(1);
      #pragma unroll
      for (int ks = 0; ks < 4; ks++) {
        bf16x8 kf[4];
        #pragma unroll
        for (int kt = 0; kt < 4; kt++) {
          int row = kt * 16 + l15;
          int ch = (ks * 4 + g) ^ (row & 7);
          kf[kt] = *(const bf16x8*)(Kc + row * 128 + ch * 8);
        }
        #pragma unroll
        for (int kt = 0; kt < 4; kt++)
          #pragma unroll
          for (int qc = 0; qc < 2; qc++)
            sacc[kt][qc] = __builtin_amdgcn_mfma_f32_16x16x32_bf16(kf[kt], qf[qc][ks], sacc[kt][qc], 0, 0, 0);
      }
      __builtin_amdgcn_s_setprio(0);
      const bool needmask = (kv0 + 63) > qw0;
      #pragma unroll
      for (int qc = 0; qc < 2; qc++) {
        int qpos = qw0 + qc * 16 + l15;
        float vmax = -INFINITY;
        #pragma unroll
        for (int kt = 0; kt < 4; kt++)
          #pragma unroll
          for (int r = 0; r < 4; r++) {
            int kvpos = kv0 + kt * 16 + g * 4 + r;
            float sv = sacc[kt][qc][r];
            if (needmask && kvpos > qpos) sv = -INFINITY;
            sacc[kt][qc][r] = sv;
            vmax = fmaxf(vmax, sv);
          }
        vmax = fmaxf(vmax, __shfl_xor(vmax, 16));
        vmax = fmaxf(vmax, __shfl_xor(vmax, 32));
        // defer-max (T13): skip rescale when growth bounded (P <= 2^8)
        if (!__all(vmax <= m2[qc] + 8.0f)) {
          float mnew = fmaxf(m2[qc], vmax);
          float resc = exp2f(m2[qc] - mnew);
          m2[qc] = mnew;
          ls[qc] *= resc;
          #pragma unroll
          for (int dc = 0; dc < 8; dc++) of[qc][dc] *= resc;
        }
        float mref = m2[qc];
        float lsum = 0.f;
        #pragma unroll
        for (int kt = 0; kt < 4; kt++)
          #pragma unroll
          for (int r = 0; r < 4; r++) {
            float p = exp2f(sacc[kt][qc][r] - mref);
            sacc[kt][qc][r] = p;
            lsum += p;
          }
        lsum += __shfl_xor(lsum, 16);
        lsum += __shfl_xor(lsum, 32);
        ls[qc] += lsum;
      }
      // pack P (two-halves k-mapping matches S^T register layout)
      bf16x8 pb[2][2];
      #pragma unroll
      for (int ktw = 0; ktw < 2; ktw++)
        #pragma unroll
        for (int qc = 0; qc < 2; qc++) {
          bf16x8 pv;
          #pragma unroll
          for (int j = 0; j < 4; j++) {
            pv[j]     = f2bf(sacc[2 * ktw][qc][j]);
            pv[4 + j] = f2bf(sacc[2 * ktw + 1][qc][j]);
          }
          pb[ktw][qc] = pv;
        }
      // O^T += V^T * P
      __builtin_amdgcn_s_setprio(1);
      #pragma unroll
      for (int ktw = 0; ktw < 2; ktw++)
        #pragma unroll
        for (int dc = 0; dc < 8; dc++) {
          int drow = dc * 16 + l15;
          const short* vp = Vt + drow * 68 + ktw * 32 + g * 4;
          short4v v1 = *(const short4v*)(vp);
          short4v v2 = *(const short4v*)(vp + 16);
          bf16x8 vf;
          #pragma unroll
          for (int j = 0; j < 4; j++) { vf[j] = v1[j]; vf[4 + j] = v2[j]; }
          #pragma unroll
          for (int qc = 0; qc < 2; qc++)
            of[qc][dc] = __builtin_amdgcn_mfma_f32_16x16x32_bf16(vf, pb[ktw][qc], of[qc][dc], 0, 0, 0);
        }
      __builtin_amdgcn_s_setprio(0);
    }

    __syncthreads();                 // drains prefetch vmcnt; all waves done with Vt / Ks[cur]
    if (haveNext) writeV();
    __syncthreads();                 // Vt(t+1) visible to all
    cur ^= 1;
  }

  // epilogue: normalize and store O (lane: q=l15, d=dc*16+4g+r)
  #pragma unroll
  for (int qc = 0; qc < 2; qc++) {
    float inv = 1.0f / ls[qc];
    size_t t = (size_t)b * T_SEQ + qw0 + qc * 16 + l15;
    short* op = og + (t * HQ + h) * HD;
    #pragma unroll
    for (int dc = 0; dc < 8; dc++) {
      short4v o;
      #pragma unroll
      for (int r = 0; r < 4; r++) o[r] = f2bf(of[qc][dc][r] * inv);
      *(short4v*)(op + dc * 16 + g * 4) = o;
    }
  }
}

extern "C" void kernel_launch(void* const* d_in, const int* in_sizes, int n_in,
                              void* d_out, int out_size, void* d_ws, size_t ws_size,
                              hipStream_t stream) {
  (void)in_sizes; (void)n_in; (void)out_size; (void)ws_size;
  const float* x  = (const float*)d_in[0];
  const float* Wq = (const float*)d_in[2];
  const float* Wk = (const float*)d_in[3];
  const float* Wv = (const float*)d_in[4];
  const float* Wo = (const float*)d_in[5];

  char* ws = (char*)d_ws;
  short* xb   = (short*)(ws);                    // 16 MB   [4096][2048]
  short* wall = (short*)(ws + 16777216);         // 12.6 MB [3072][2048] = WqT|WkT|WvT
  short* wkT  = wall + (size_t)2048 * 2048;
  short* wvT  = wall + (size_t)2560 * 2048;
  short* woT  = (short*)(ws + 29360128);         // 8 MB    [2048][2048]
  short* qb   = (short*)(ws + 37748736);         // 16 MB   [B,T,HQ,128]
  short* kb   = (short*)(ws + 54525952);         // 4 MB    [B,T,HKV,128]
  short* vb   = (short*)(ws + 58720256);         // 4 MB    [B,T,HKV,128]
  short* ab   = (short*)(ws + 62914560);         // 16 MB   [4096][2048]

  const float MULT = 0.08838834764831845f;
  const float LOG2E = 1.4426950408889634f;
  const float QSCALE = MULT * LOG2E;

  dim3 tb(32, 8);
  cvt_kernel<<<8192, 256, 0, stream>>>(x, xb, 8388608);
  transpose_cvt<<<dim3(64, 64), tb, 0, stream>>>(Wq, wall, 2048, 2048);
  transpose_cvt<<<dim3(16, 64), tb, 0, stream>>>(Wk, wkT, 2048, 512);
  transpose_cvt<<<dim3(16, 64), tb, 0, stream>>>(Wv, wvT, 2048, 512);
  transpose_cvt<<<dim3(64, 64), tb, 0, stream>>>(Wo, woT, 2048, 2048);

  // fused QKV projection: [4096][2048] x [2048][3072] -> qb|kb|vb
  gemm_kernel<2><<<dim3(24, 32), 256, 0, stream>>>(xb, wall, qb, kb, vb, 4096, 3072, 2048);

  rope_kernel<<<16384, 256, 0, stream>>>(qb, HQ, QSCALE, 4194304);
  rope_kernel<<<4096, 256, 0, stream>>>(kb, HKV, 1.0f, 1048576);

  attn_kernel<<<dim3(16, 16, 2), 256, 0, stream>>>(qb, kb, vb, ab);

  gemm_kernel<1><<<dim3(16, 32), 256, 0, stream>>>(ab, woT, d_out, nullptr, nullptr, 4096, 2048, 2048);
}